// Round 18
// baseline (827.634 us; speedup 1.0000x reference)
//
#include <hip/hip_runtime.h>
#include <cstdint>
#include <cstddef>

typedef short short8 __attribute__((ext_vector_type(8)));
typedef float f32x4 __attribute__((ext_vector_type(4)));
typedef int   i32x4 __attribute__((ext_vector_type(4)));

#define NPATCH 262144
#define NBAGS  32
#define IN_DIM 1024
#define F_DIM  256
#define A_DIM  128
#define ROWSB  256
#define NBLK   (NPATCH / ROWSB)    // 1024

__device__ __forceinline__ unsigned short f2bf(float f){
  uint32_t u = __builtin_bit_cast(uint32_t, f);
  u += 0x7fffu + ((u >> 16) & 1u);
  return (unsigned short)(u >> 16);
}
__device__ __forceinline__ float bf2f(unsigned short h){
  return __builtin_bit_cast(float, (uint32_t)h << 16);
}
__device__ __forceinline__ float tanh_fast(float x){
  float e = __expf(2.f * x);
  return (e - 1.f) * __builtin_amdgcn_rcpf(e + 1.f);
}
__device__ __forceinline__ uint32_t cvtpk(float a, float b){
  uint32_t r;
  asm("v_cvt_pk_bf16_f32 %0, %1, %2" : "=v"(r) : "v"(a), "v"(b));
  return r;
}
__device__ __forceinline__ void gload_lds16(const void* g, void* l){
  __builtin_amdgcn_global_load_lds((const __attribute__((address_space(1))) void*)g,
                                   (__attribute__((address_space(3))) void*)l, 16, 0, 0);
}

#define MFMA(a,b,c) __builtin_amdgcn_mfma_f32_16x16x32_bf16((a),(b),(c),0,0,0)
#define SWZH(r) (((r) & 7) << 4)   // 512B bf16 Hs rows

// ---------- prep: W1, Wa1 -> bf16 in ws; zero bag accumulators ----------
__global__ void prep_kernel(const float* __restrict__ W1, const float* __restrict__ Wa1,
                            unsigned short* __restrict__ w1b, unsigned short* __restrict__ wa1b,
                            float* __restrict__ bagAcc){
  int id = blockIdx.x * 256 + threadIdx.x;
  if (id < F_DIM*IN_DIM) {
    w1b[id] = f2bf(W1[id]);
  } else if (id < F_DIM*IN_DIM + A_DIM*F_DIM) {
    int j = id - F_DIM*IN_DIM;
    wa1b[j] = f2bf(Wa1[j]);
  } else if (id < F_DIM*IN_DIM + A_DIM*F_DIM + NBAGS*257) {
    bagAcc[id - (F_DIM*IN_DIM + A_DIM*F_DIM)] = 0.f;
  }
}

// ---------- fused main ----------
// 256 rows/block, 512 threads = 8 waves; wave = 32 rows x ALL 256 cols
// (acc[2][16] f32x4 = 128 VGPR; ~200 total; launch_bounds(512,1) -> no spill
// under either launch-bounds semantics). R14's EXACT group pipeline, with
// ROWSB=256 halving B re-stage traffic: port bytes 1.61GB (was 2.14GB).
//   16 groups of BK=64 (2 steps of k=32):
//     A: register stream, 2 rows x 32B/thread/step, depth-2 ping-pong,
//        prefetch issued one group ahead, crosses the group barrier.
//     B: [256 cols][64k] bf16 32KB tile, double-buffered; stage(g+1) = 4
//        gload_lds/wave at group start; group-end vmcnt(8) retires it,
//        keeps the 8 A prefetch loads in flight.
// Epilogue: TWO sequential 128-row halves (Hs 64KB overlays Bt0/Bt1).
// LDS 74240: Bt0 @0 | Bt1 @32K | Hs overlay @0 | sc8[128][8] @64K |
//   evec[128] | Pp[4][256]. 1 block/CU.
__global__ __launch_bounds__(512, 1)
void mil_main(const float* __restrict__ feat,
              const unsigned short* __restrict__ w1b,
              const float* __restrict__ b1,
              const unsigned short* __restrict__ wa1b,
              const float* __restrict__ ba1,
              const float* __restrict__ wa2,
              const float* __restrict__ ba2v,
              float* __restrict__ bagAcc)
{
  extern __shared__ char lds[];
  char* Bt0 = lds;                      // [256 cols][128B], swizzled k
  char* Bt1 = lds + 32768;
  char* HsB = lds;                      // epilogue overlay (per 128-row half)
  float* sc8  = (float*)(lds + 65536);              // [128][8]
  float* evec = (float*)(lds + 65536 + 4096);       // [128]
  float* Pp   = (float*)(lds + 65536 + 4096 + 512); // [4][256]

  const int tid  = threadIdx.x;
  const int wid  = tid >> 6;            // 0..7
  const int lane = tid & 63;
  const int l15  = lane & 15;
  const int l4   = lane >> 4;
  const int bRow = blockIdx.x * ROWSB;
  const int wRow = wid * 32;            // this wave's private 32 rows

  // ---- A register stream: rows wRow+l15 and wRow+16+l15, k-chunk l4*8 ----
  const float* aG0 = feat + (size_t)(bRow + wRow + l15) * IN_DIM + l4*8;
  const float* aG1 = aG0 + (size_t)16 * IN_DIM;

  // ---- B stage source (linear LDS dest, pre-swizzled global src) ----
  // D(i) = wid*4096 + i*1024 + lane*16; col = wid*32 + i*8 + (lane>>3);
  // kb = (lane&7)*16; src = w1b + col*2048 + g*128 + (kb ^ ((col&7)<<4)).
  // i -> i+1: col += 8 (same swizzle bits) -> src += 16384.
  const char* srcB = (const char*)w1b
      + (size_t)(wid*32 + (lane >> 3)) * 2048
      + (((lane & 7) * 16) ^ (((lane >> 3) & 7) << 4));

#define STAGEB(bb, g) do { \
    _Pragma("unroll") \
    for (int i_ = 0; i_ < 4; ++i_) \
      gload_lds16(srcB + (size_t)i_*16384 + (size_t)(g)*128, \
                  (bb) + wid*4096 + i_*1024); \
  } while(0)

#define LOADA(R, t) do { \
    const float* p0_ = aG0 + (t)*32; \
    const float* p1_ = aG1 + (t)*32; \
    R[0] = *(const float4*)p0_;  R[1] = *(const float4*)(p0_ + 4); \
    R[2] = *(const float4*)p1_;  R[3] = *(const float4*)(p1_ + 4); \
  } while(0)

#define AFRAG2(a0, a1, R) do { \
    const float* v_ = (const float*)(R); \
    i32x4 w0_ = { (int)cvtpk(v_[0],  v_[1]),  (int)cvtpk(v_[2],  v_[3]), \
                  (int)cvtpk(v_[4],  v_[5]),  (int)cvtpk(v_[6],  v_[7]) }; \
    i32x4 w1_ = { (int)cvtpk(v_[8],  v_[9]),  (int)cvtpk(v_[10], v_[11]), \
                  (int)cvtpk(v_[12], v_[13]), (int)cvtpk(v_[14], v_[15]) }; \
    a0 = __builtin_bit_cast(short8, w0_); \
    a1 = __builtin_bit_cast(short8, w1_); \
  } while(0)

  f32x4 acc[2][16];
  #pragma unroll
  for (int i = 0; i < 2; ++i)
    #pragma unroll
    for (int j = 0; j < 16; ++j) acc[i][j] = (f32x4){0.f, 0.f, 0.f, 0.f};

  float4 aR0[4], aR1[4];

  // prologue: stage B(0) [4]; A(0),A(1) -> regs [8]; vmcnt(8) retires stage
  STAGEB(Bt0, 0);
  LOADA(aR0, 0);
  LOADA(aR1, 1);
  asm volatile("s_waitcnt vmcnt(8)" ::: "memory");
  __builtin_amdgcn_sched_barrier(0);
  __builtin_amdgcn_s_barrier();

  const int swzk = (l15 & 7) << 4;
  const int rb   = l15 * 128;

  for (int g = 0; g < 16; ++g){
    const char* bb = (g & 1) ? Bt1 : Bt0;
    char*       bn = (g & 1) ? Bt0 : Bt1;
    if (g < 15) STAGEB(bn, g + 1);      // in flight across the whole group
    __builtin_amdgcn_sched_barrier(0);

    #pragma unroll
    for (int s = 0; s < 2; ++s){
      short8 af0, af1;
      if (s == 0){
        AFRAG2(af0, af1, aR0);          // waits A(2g), issued one group ago
        if (g < 15) LOADA(aR0, 2*g + 2);
      } else {
        AFRAG2(af0, af1, aR1);
        if (g < 15) LOADA(aR1, 2*g + 3);
      }
      __builtin_amdgcn_sched_barrier(0);
      const int off = rb + ((s*64 + l4*16) ^ swzk);
      #pragma unroll
      for (int nf = 0; nf < 16; ++nf){
        short8 bf = *(const short8*)(bb + nf*2048 + off);
        acc[0][nf] = MFMA(af0, bf, acc[0][nf]);
        acc[1][nf] = MFMA(af1, bf, acc[1][nf]);
      }
    }
    // retire stage(g+1) (oldest 4); keep the 8 A prefetch loads in flight
    asm volatile("s_waitcnt vmcnt(8) lgkmcnt(0)" ::: "memory");
    __builtin_amdgcn_sched_barrier(0);
    __builtin_amdgcn_s_barrier();
  }
  __syncthreads();   // full drain; Bt region free for Hs overlay

#undef STAGEB
#undef LOADA
#undef AFRAG2

  // ======== epilogue: two sequential 128-row halves ========
  const int bag = bRow >> 13;   // 8192 rows per bag; block inside one bag
  for (int hh = 0; hh < 2; ++hh){
    // ---- bias + relu, h(half) -> Hs[128][256] bf16 (swizzled) ----
    if ((wid >> 2) == hh){
      #pragma unroll
      for (int nf = 0; nf < 16; ++nf){
        float b1v = b1[nf*16 + l15];
        #pragma unroll
        for (int mf = 0; mf < 2; ++mf)
          #pragma unroll
          for (int r = 0; r < 4; ++r){
            int lr  = (wid & 3)*32 + mf*16 + l4*4 + r;   // local row in half
            int col = nf*16 + l15;
            float v = fmaxf(acc[mf][nf][r] + b1v, 0.f);
            int by = (lr*512 + col*2) ^ SWZH(lr);
            *(unsigned short*)(HsB + by) = f2bf(v);
          }
      }
    }
    __syncthreads();

    // ---- GEMM2: a = h @ Wa1.T (M=128 local, N=128, K=256) ----
    // wave wid owns acols [wid*16, wid*16+16) x all 128 local rows
    {
      const int acol = wid*16 + l15;
      f32x4 acc2[8];
      #pragma unroll
      for (int i = 0; i < 8; ++i) acc2[i] = (f32x4){0.f, 0.f, 0.f, 0.f};

      #pragma unroll
      for (int ks2 = 0; ks2 < 8; ++ks2){
        short8 wf = *(const short8*)(const void*)(wa1b + acol*256 + ks2*32 + l4*8);
        #pragma unroll
        for (int mf = 0; mf < 8; ++mf){
          int lr = mf*16 + l15;
          int by = (lr*512 + (ks2*32 + l4*8)*2) ^ SWZH(lr);
          short8 hf = *(const short8*)(HsB + by);
          acc2[mf] = MFMA(hf, wf, acc2[mf]);
        }
      }

      const float ba1v = ba1[acol];
      const float wa2v = wa2[acol];
      #pragma unroll
      for (int mf = 0; mf < 8; ++mf)
        #pragma unroll
        for (int r = 0; r < 4; ++r){
          float p = tanh_fast(acc2[mf][r] + ba1v) * wa2v;
          p += __shfl_xor(p, 1);
          p += __shfl_xor(p, 2);
          p += __shfl_xor(p, 4);
          p += __shfl_xor(p, 8);
          if (l15 == 0){
            int lr = mf*16 + l4*4 + r;
            sc8[lr*8 + wid] = p;
          }
        }
    }
    __syncthreads();

    if (tid < 128){
      float s = sc8[tid*8+0] + sc8[tid*8+1] + sc8[tid*8+2] + sc8[tid*8+3]
              + sc8[tid*8+4] + sc8[tid*8+5] + sc8[tid*8+6] + sc8[tid*8+7]
              + ba2v[0];
      evec[tid] = __expf(s);   // |s| <= ~2.2 (tanh-bounded) — no max-subtract
    }
    __syncthreads();

    // ---- weighted partial reduce: P[f] = sum_r e[r]*h[r][f] ----
    {
      const int f0 = (tid & 127) << 1;
      const int g  = tid >> 7;           // 4 row groups of 32
      float p0 = 0.f, p1 = 0.f;
      const int rbase = g << 5;
      #pragma unroll 8
      for (int i = 0; i < 32; ++i){
        const int r = rbase + i;
        const uint32_t hw = *(const uint32_t*)(HsB + ((r*512 + f0*2) ^ SWZH(r)));
        const float e = evec[r];
        p0 = fmaf(e, bf2f((unsigned short)(hw & 0xffffu)), p0);
        p1 = fmaf(e, bf2f((unsigned short)(hw >> 16)),     p1);
      }
      Pp[(g << 8) + f0]     = p0;
      Pp[(g << 8) + f0 + 1] = p1;
    }
    __syncthreads();

    if (tid < 256){
      float s = Pp[tid] + Pp[256 + tid] + Pp[512 + tid] + Pp[768 + tid];
      atomicAdd(&bagAcc[bag*257 + tid], s);
    }
    if (tid < 64){
      float se = evec[tid] + evec[tid + 64];
      se += __shfl_xor(se, 1);
      se += __shfl_xor(se, 2);
      se += __shfl_xor(se, 4);
      se += __shfl_xor(se, 8);
      se += __shfl_xor(se, 16);
      se += __shfl_xor(se, 32);
      if (tid == 0) atomicAdd(&bagAcc[bag*257 + 256], se);
    }
    __syncthreads();   // protect Hs/sc8/evec/Pp before next half overwrites
  }
}

// ---------- head: out[b,d] = (P[b]/E[b]) . Wh[d] + bh[d] ----------
__global__ void head_kernel(const float* __restrict__ bagAcc,
                            const float* __restrict__ wh,
                            const float* __restrict__ bh,
                            float* __restrict__ out){
  int t = threadIdx.x;          // 64 threads: b = t>>1, d = t&1
  int b = t >> 1, d = t & 1;
  const float* P = bagAcc + b*257;
  float invE = 1.f / P[256];
  float acc = 0.f;
  for (int f = 0; f < 256; ++f) acc += P[f] * wh[d*256 + f];
  out[b*2 + d] = acc * invE + bh[d];
}

extern "C" void kernel_launch(void* const* d_in, const int* in_sizes, int n_in,
                              void* d_out, int out_size, void* d_ws, size_t ws_size,
                              hipStream_t stream){
  const float* feat = (const float*)d_in[0];
  const float* W1   = (const float*)d_in[1];
  const float* b1   = (const float*)d_in[2];
  const float* Wa1  = (const float*)d_in[3];
  const float* ba1  = (const float*)d_in[4];
  const float* Wa2  = (const float*)d_in[5];
  const float* ba2  = (const float*)d_in[6];
  const float* Wh   = (const float*)d_in[7];
  const float* bh   = (const float*)d_in[8];
  // d_in[9]: bag_sizes — uniform 8192 (N_PATCHES/N_BAGS), bags contiguous.

  unsigned short* w1b  = (unsigned short*)d_ws;                        // 512 KB
  unsigned short* wa1b = (unsigned short*)((char*)d_ws + 524288);      // 64 KB
  float* bagAcc        = (float*)((char*)d_ws + 589824);               // 32*257 f32

  const size_t ldsBytes = 65536 + 4096 + 512 + 4096;   // 74240
  hipFuncSetAttribute((const void*)mil_main,
                      hipFuncAttributeMaxDynamicSharedMemorySize, (int)ldsBytes);

  prep_kernel<<<1185, 256, 0, stream>>>(W1, Wa1, w1b, wa1b, bagAcc);

  mil_main<<<NBLK, 512, ldsBytes, stream>>>(feat, w1b, b1, wa1b, ba1,
                                            Wa2, ba2, bagAcc);

  head_kernel<<<1, 64, 0, stream>>>(bagAcc, Wh, bh, (float*)d_out);
}

// Round 19
// 827.423 us; speedup vs baseline: 1.0003x; 1.0003x over previous
//
#include <hip/hip_runtime.h>
#include <cstdint>
#include <cstddef>

typedef short short8 __attribute__((ext_vector_type(8)));
typedef float f32x4 __attribute__((ext_vector_type(4)));
typedef int   i32x4 __attribute__((ext_vector_type(4)));

#define NPATCH 262144
#define NBAGS  32
#define IN_DIM 1024
#define F_DIM  256
#define A_DIM  128
#define ROWSB  256
#define NBLK   (NPATCH / ROWSB)    // 1024

__device__ __forceinline__ unsigned short f2bf(float f){
  uint32_t u = __builtin_bit_cast(uint32_t, f);
  u += 0x7fffu + ((u >> 16) & 1u);
  return (unsigned short)(u >> 16);
}
__device__ __forceinline__ float bf2f(unsigned short h){
  return __builtin_bit_cast(float, (uint32_t)h << 16);
}
__device__ __forceinline__ float tanh_fast(float x){
  float e = __expf(2.f * x);
  return (e - 1.f) * __builtin_amdgcn_rcpf(e + 1.f);
}
__device__ __forceinline__ uint32_t cvtpk(float a, float b){
  uint32_t r;
  asm("v_cvt_pk_bf16_f32 %0, %1, %2" : "=v"(r) : "v"(a), "v"(b));
  return r;
}
__device__ __forceinline__ void gload_lds16(const void* g, void* l){
  __builtin_amdgcn_global_load_lds((const __attribute__((address_space(1))) void*)g,
                                   (__attribute__((address_space(3))) void*)l, 16, 0, 0);
}

#define MFMA(a,b,c) __builtin_amdgcn_mfma_f32_16x16x32_bf16((a),(b),(c),0,0,0)
#define SWZH(r) (((r) & 7) << 4)   // 512B bf16 Hs rows

// ---------- prep: W1, Wa1 -> bf16 in ws; zero bag accumulators ----------
__global__ void prep_kernel(const float* __restrict__ W1, const float* __restrict__ Wa1,
                            unsigned short* __restrict__ w1b, unsigned short* __restrict__ wa1b,
                            float* __restrict__ bagAcc){
  int id = blockIdx.x * 256 + threadIdx.x;
  if (id < F_DIM*IN_DIM) {
    w1b[id] = f2bf(W1[id]);
  } else if (id < F_DIM*IN_DIM + A_DIM*F_DIM) {
    int j = id - F_DIM*IN_DIM;
    wa1b[j] = f2bf(Wa1[j]);
  } else if (id < F_DIM*IN_DIM + A_DIM*F_DIM + NBAGS*257) {
    bagAcc[id - (F_DIM*IN_DIM + A_DIM*F_DIM)] = 0.f;
  }
}

// ---------- fused main (R18 kernel; ONLY the launch attribute changed) ----------
// 256 rows/block, 512 threads = 8 waves; wave = 32 rows x ALL 256 cols
// (acc[2][16] f32x4 = 128 VGPR; ~200 total). amdgpu_waves_per_eu(2) sets the
// VGPR budget to 256/wave (R17/R18's __launch_bounds__ spellings made hipcc
// cap at 128 -> 60+ spilled regs -> 547MB scratch writes; this attribute is
// the documented way to request the 2-waves/EU budget).
//   16 groups of BK=64 (2 steps of k=32):
//     A: register stream, 2 rows x 32B/thread/step, depth-2 ping-pong,
//        prefetch issued one group ahead, crosses the group barrier.
//     B: [256 cols][64k] bf16 32KB tile, double-buffered; stage(g+1) = 4
//        gload_lds/wave at group start; group-end vmcnt(8) retires it.
//   Port bytes 1.61GB (A 1.07 HBM + B 0.54 L2) at the measured ~34 GB/s/CU
//   VMEM rate -> ~195us K-loop (R14 = 2.25GB -> 258us).
// Epilogue: TWO sequential 128-row halves (Hs 64KB overlays Bt0/Bt1).
// LDS 74240. 1 block/CU.
__global__ __attribute__((amdgpu_flat_work_group_size(512, 512), amdgpu_waves_per_eu(2)))
void mil_main(const float* __restrict__ feat,
              const unsigned short* __restrict__ w1b,
              const float* __restrict__ b1,
              const unsigned short* __restrict__ wa1b,
              const float* __restrict__ ba1,
              const float* __restrict__ wa2,
              const float* __restrict__ ba2v,
              float* __restrict__ bagAcc)
{
  extern __shared__ char lds[];
  char* Bt0 = lds;                      // [256 cols][128B], swizzled k
  char* Bt1 = lds + 32768;
  char* HsB = lds;                      // epilogue overlay (per 128-row half)
  float* sc8  = (float*)(lds + 65536);              // [128][8]
  float* evec = (float*)(lds + 65536 + 4096);       // [128]
  float* Pp   = (float*)(lds + 65536 + 4096 + 512); // [4][256]

  const int tid  = threadIdx.x;
  const int wid  = tid >> 6;            // 0..7
  const int lane = tid & 63;
  const int l15  = lane & 15;
  const int l4   = lane >> 4;
  const int bRow = blockIdx.x * ROWSB;
  const int wRow = wid * 32;            // this wave's private 32 rows

  // ---- A register stream: rows wRow+l15 and wRow+16+l15, k-chunk l4*8 ----
  const float* aG0 = feat + (size_t)(bRow + wRow + l15) * IN_DIM + l4*8;
  const float* aG1 = aG0 + (size_t)16 * IN_DIM;

  // ---- B stage source (linear LDS dest, pre-swizzled global src) ----
  const char* srcB = (const char*)w1b
      + (size_t)(wid*32 + (lane >> 3)) * 2048
      + (((lane & 7) * 16) ^ (((lane >> 3) & 7) << 4));

#define STAGEB(bb, g) do { \
    _Pragma("unroll") \
    for (int i_ = 0; i_ < 4; ++i_) \
      gload_lds16(srcB + (size_t)i_*16384 + (size_t)(g)*128, \
                  (bb) + wid*4096 + i_*1024); \
  } while(0)

#define LOADA(R, t) do { \
    const float* p0_ = aG0 + (t)*32; \
    const float* p1_ = aG1 + (t)*32; \
    R[0] = *(const float4*)p0_;  R[1] = *(const float4*)(p0_ + 4); \
    R[2] = *(const float4*)p1_;  R[3] = *(const float4*)(p1_ + 4); \
  } while(0)

#define AFRAG2(a0, a1, R) do { \
    const float* v_ = (const float*)(R); \
    i32x4 w0_ = { (int)cvtpk(v_[0],  v_[1]),  (int)cvtpk(v_[2],  v_[3]), \
                  (int)cvtpk(v_[4],  v_[5]),  (int)cvtpk(v_[6],  v_[7]) }; \
    i32x4 w1_ = { (int)cvtpk(v_[8],  v_[9]),  (int)cvtpk(v_[10], v_[11]), \
                  (int)cvtpk(v_[12], v_[13]), (int)cvtpk(v_[14], v_[15]) }; \
    a0 = __builtin_bit_cast(short8, w0_); \
    a1 = __builtin_bit_cast(short8, w1_); \
  } while(0)

  f32x4 acc[2][16];
  #pragma unroll
  for (int i = 0; i < 2; ++i)
    #pragma unroll
    for (int j = 0; j < 16; ++j) acc[i][j] = (f32x4){0.f, 0.f, 0.f, 0.f};

  float4 aR0[4], aR1[4];

  // prologue: stage B(0) [4]; A(0),A(1) -> regs [8]; vmcnt(8) retires stage
  STAGEB(Bt0, 0);
  LOADA(aR0, 0);
  LOADA(aR1, 1);
  asm volatile("s_waitcnt vmcnt(8)" ::: "memory");
  __builtin_amdgcn_sched_barrier(0);
  __builtin_amdgcn_s_barrier();

  const int swzk = (l15 & 7) << 4;
  const int rb   = l15 * 128;

  for (int g = 0; g < 16; ++g){
    const char* bb = (g & 1) ? Bt1 : Bt0;
    char*       bn = (g & 1) ? Bt0 : Bt1;
    if (g < 15) STAGEB(bn, g + 1);      // in flight across the whole group
    __builtin_amdgcn_sched_barrier(0);

    #pragma unroll
    for (int s = 0; s < 2; ++s){
      short8 af0, af1;
      if (s == 0){
        AFRAG2(af0, af1, aR0);          // waits A(2g), issued one group ago
        if (g < 15) LOADA(aR0, 2*g + 2);
      } else {
        AFRAG2(af0, af1, aR1);
        if (g < 15) LOADA(aR1, 2*g + 3);
      }
      __builtin_amdgcn_sched_barrier(0);
      const int off = rb + ((s*64 + l4*16) ^ swzk);
      #pragma unroll
      for (int nf = 0; nf < 16; ++nf){
        short8 bf = *(const short8*)(bb + nf*2048 + off);
        acc[0][nf] = MFMA(af0, bf, acc[0][nf]);
        acc[1][nf] = MFMA(af1, bf, acc[1][nf]);
      }
    }
    // retire stage(g+1) (oldest 4); keep the 8 A prefetch loads in flight
    asm volatile("s_waitcnt vmcnt(8) lgkmcnt(0)" ::: "memory");
    __builtin_amdgcn_sched_barrier(0);
    __builtin_amdgcn_s_barrier();
  }
  __syncthreads();   // full drain; Bt region free for Hs overlay

#undef STAGEB
#undef LOADA
#undef AFRAG2

  // ======== epilogue: two sequential 128-row halves ========
  const int bag = bRow >> 13;   // 8192 rows per bag; block inside one bag
  for (int hh = 0; hh < 2; ++hh){
    // ---- bias + relu, h(half) -> Hs[128][256] bf16 (swizzled) ----
    if ((wid >> 2) == hh){
      #pragma unroll
      for (int nf = 0; nf < 16; ++nf){
        float b1v = b1[nf*16 + l15];
        #pragma unroll
        for (int mf = 0; mf < 2; ++mf)
          #pragma unroll
          for (int r = 0; r < 4; ++r){
            int lr  = (wid & 3)*32 + mf*16 + l4*4 + r;   // local row in half
            int col = nf*16 + l15;
            float v = fmaxf(acc[mf][nf][r] + b1v, 0.f);
            int by = (lr*512 + col*2) ^ SWZH(lr);
            *(unsigned short*)(HsB + by) = f2bf(v);
          }
      }
    }
    __syncthreads();

    // ---- GEMM2: a = h @ Wa1.T (M=128 local, N=128, K=256) ----
    {
      const int acol = wid*16 + l15;
      f32x4 acc2[8];
      #pragma unroll
      for (int i = 0; i < 8; ++i) acc2[i] = (f32x4){0.f, 0.f, 0.f, 0.f};

      #pragma unroll
      for (int ks2 = 0; ks2 < 8; ++ks2){
        short8 wf = *(const short8*)(const void*)(wa1b + acol*256 + ks2*32 + l4*8);
        #pragma unroll
        for (int mf = 0; mf < 8; ++mf){
          int lr = mf*16 + l15;
          int by = (lr*512 + (ks2*32 + l4*8)*2) ^ SWZH(lr);
          short8 hf = *(const short8*)(HsB + by);
          acc2[mf] = MFMA(hf, wf, acc2[mf]);
        }
      }

      const float ba1v = ba1[acol];
      const float wa2v = wa2[acol];
      #pragma unroll
      for (int mf = 0; mf < 8; ++mf)
        #pragma unroll
        for (int r = 0; r < 4; ++r){
          float p = tanh_fast(acc2[mf][r] + ba1v) * wa2v;
          p += __shfl_xor(p, 1);
          p += __shfl_xor(p, 2);
          p += __shfl_xor(p, 4);
          p += __shfl_xor(p, 8);
          if (l15 == 0){
            int lr = mf*16 + l4*4 + r;
            sc8[lr*8 + wid] = p;
          }
        }
    }
    __syncthreads();

    if (tid < 128){
      float s = sc8[tid*8+0] + sc8[tid*8+1] + sc8[tid*8+2] + sc8[tid*8+3]
              + sc8[tid*8+4] + sc8[tid*8+5] + sc8[tid*8+6] + sc8[tid*8+7]
              + ba2v[0];
      evec[tid] = __expf(s);   // |s| <= ~2.2 (tanh-bounded) — no max-subtract
    }
    __syncthreads();

    // ---- weighted partial reduce: P[f] = sum_r e[r]*h[r][f] ----
    {
      const int f0 = (tid & 127) << 1;
      const int g  = tid >> 7;           // 4 row groups of 32
      float p0 = 0.f, p1 = 0.f;
      const int rbase = g << 5;
      #pragma unroll 8
      for (int i = 0; i < 32; ++i){
        const int r = rbase + i;
        const uint32_t hw = *(const uint32_t*)(HsB + ((r*512 + f0*2) ^ SWZH(r)));
        const float e = evec[r];
        p0 = fmaf(e, bf2f((unsigned short)(hw & 0xffffu)), p0);
        p1 = fmaf(e, bf2f((unsigned short)(hw >> 16)),     p1);
      }
      Pp[(g << 8) + f0]     = p0;
      Pp[(g << 8) + f0 + 1] = p1;
    }
    __syncthreads();

    if (tid < 256){
      float s = Pp[tid] + Pp[256 + tid] + Pp[512 + tid] + Pp[768 + tid];
      atomicAdd(&bagAcc[bag*257 + tid], s);
    }
    if (tid < 64){
      float se = evec[tid] + evec[tid + 64];
      se += __shfl_xor(se, 1);
      se += __shfl_xor(se, 2);
      se += __shfl_xor(se, 4);
      se += __shfl_xor(se, 8);
      se += __shfl_xor(se, 16);
      se += __shfl_xor(se, 32);
      if (tid == 0) atomicAdd(&bagAcc[bag*257 + 256], se);
    }
    __syncthreads();   // protect Hs/sc8/evec/Pp before next half overwrites
  }
}

// ---------- head: out[b,d] = (P[b]/E[b]) . Wh[d] + bh[d] ----------
__global__ void head_kernel(const float* __restrict__ bagAcc,
                            const float* __restrict__ wh,
                            const float* __restrict__ bh,
                            float* __restrict__ out){
  int t = threadIdx.x;          // 64 threads: b = t>>1, d = t&1
  int b = t >> 1, d = t & 1;
  const float* P = bagAcc + b*257;
  float invE = 1.f / P[256];
  float acc = 0.f;
  for (int f = 0; f < 256; ++f) acc += P[f] * wh[d*256 + f];
  out[b*2 + d] = acc * invE + bh[d];
}

extern "C" void kernel_launch(void* const* d_in, const int* in_sizes, int n_in,
                              void* d_out, int out_size, void* d_ws, size_t ws_size,
                              hipStream_t stream){
  const float* feat = (const float*)d_in[0];
  const float* W1   = (const float*)d_in[1];
  const float* b1   = (const float*)d_in[2];
  const float* Wa1  = (const float*)d_in[3];
  const float* ba1  = (const float*)d_in[4];
  const float* Wa2  = (const float*)d_in[5];
  const float* ba2  = (const float*)d_in[6];
  const float* Wh   = (const float*)d_in[7];
  const float* bh   = (const float*)d_in[8];
  // d_in[9]: bag_sizes — uniform 8192 (N_PATCHES/N_BAGS), bags contiguous.

  unsigned short* w1b  = (unsigned short*)d_ws;                        // 512 KB
  unsigned short* wa1b = (unsigned short*)((char*)d_ws + 524288);      // 64 KB
  float* bagAcc        = (float*)((char*)d_ws + 589824);               // 32*257 f32

  const size_t ldsBytes = 65536 + 4096 + 512 + 4096;   // 74240
  hipFuncSetAttribute((const void*)mil_main,
                      hipFuncAttributeMaxDynamicSharedMemorySize, (int)ldsBytes);

  prep_kernel<<<1185, 256, 0, stream>>>(W1, Wa1, w1b, wa1b, bagAcc);

  mil_main<<<NBLK, 512, ldsBytes, stream>>>(feat, w1b, b1, wa1b, ba1,
                                            Wa2, ba2, bagAcc);

  head_kernel<<<1, 64, 0, stream>>>(bagAcc, Wh, bh, (float*)d_out);
}

// Round 20
// 289.696 us; speedup vs baseline: 2.8569x; 2.8562x over previous
//
#include <hip/hip_runtime.h>
#include <cstdint>
#include <cstddef>

typedef short short8 __attribute__((ext_vector_type(8)));
typedef float f32x4 __attribute__((ext_vector_type(4)));
typedef int   i32x4 __attribute__((ext_vector_type(4)));

#define NPATCH 262144
#define NBAGS  32
#define IN_DIM 1024
#define F_DIM  256
#define A_DIM  128
#define ROWSB  128
#define NBLK   (NPATCH / ROWSB)    // 2048

__device__ __forceinline__ unsigned short f2bf(float f){
  uint32_t u = __builtin_bit_cast(uint32_t, f);
  u += 0x7fffu + ((u >> 16) & 1u);
  return (unsigned short)(u >> 16);
}
__device__ __forceinline__ float bf2f(unsigned short h){
  return __builtin_bit_cast(float, (uint32_t)h << 16);
}
__device__ __forceinline__ float tanh_fast(float x){
  float e = __expf(2.f * x);
  return (e - 1.f) * __builtin_amdgcn_rcpf(e + 1.f);
}
__device__ __forceinline__ uint32_t cvtpk(float a, float b){
  uint32_t r;
  asm("v_cvt_pk_bf16_f32 %0, %1, %2" : "=v"(r) : "v"(a), "v"(b));
  return r;
}
__device__ __forceinline__ void gload_lds16(const void* g, void* l){
  __builtin_amdgcn_global_load_lds((const __attribute__((address_space(1))) void*)g,
                                   (__attribute__((address_space(3))) void*)l, 16, 0, 0);
}

#define MFMA(a,b,c) __builtin_amdgcn_mfma_f32_16x16x32_bf16((a),(b),(c),0,0,0)
#define SWZH(r) (((r) & 7) << 4)   // 512B bf16 Hs rows

// ---------- prep: W1, Wa1 -> bf16 in ws; zero bag accumulators ----------
__global__ void prep_kernel(const float* __restrict__ W1, const float* __restrict__ Wa1,
                            unsigned short* __restrict__ w1b, unsigned short* __restrict__ wa1b,
                            float* __restrict__ bagAcc){
  int id = blockIdx.x * 256 + threadIdx.x;
  if (id < F_DIM*IN_DIM) {
    w1b[id] = f2bf(W1[id]);
  } else if (id < F_DIM*IN_DIM + A_DIM*F_DIM) {
    int j = id - F_DIM*IN_DIM;
    wa1b[j] = f2bf(Wa1[j]);
  } else if (id < F_DIM*IN_DIM + A_DIM*F_DIM + NBAGS*257) {
    bagAcc[id - (F_DIM*IN_DIM + A_DIM*F_DIM)] = 0.f;
  }
}

// ---------- fused main (R14 — best measured: 290us total) ----------
// 128 rows/block, 256 threads, 4 waves; wave = 32 rows x ALL 256 cols
// (acc[2][16] f32x4 = 128 VGPR). A rows are wave-private -> A read ONCE.
// GEMM1: 16 groups of BK=64 (2 MFMA-steps of k=32 each).
//   A: pure register stream (probe-validated at HBM floor): per step each
//      thread holds 2 rows x 32B fp32, depth-2 ping-pong, consume-then-reload.
//   B: [256 cols][64k] bf16 tile (32KB), DOUBLE-buffered: stage(g+1) issued
//      at group start via 8 gload_lds (linear dest, pre-swizzled src),
//      retired by counted vmcnt(8) at group END -> full group of overlap.
//   One barrier + one counted wait per group (16 total). No A ds_writes.
// Port-traffic accounting (the binding resource, ~34 GB/s/CU measured):
//   A 1.07GB (HBM) + B 1.07GB (L2 restage) + epilogue ~0.1GB = 2.25GB
//   -> ~258us mil_main = structural ceiling for ROWSB=128 (ROWSB=256 is
//   blocked: >=512-thread blocks spill at 128 arch-VGPR on this toolchain).
// LDS 70144: Bt0 @0 (32K) | Bt1 @32K | epilogue overlay: Hs[128][256] @0
//   (64K) | sc4[128][4] @64K | evec[128] @+2048 | Pp[2][256] @+2560.
__global__ __launch_bounds__(256, 2)
void mil_main(const float* __restrict__ feat,
              const unsigned short* __restrict__ w1b,
              const float* __restrict__ b1,
              const unsigned short* __restrict__ wa1b,
              const float* __restrict__ ba1,
              const float* __restrict__ wa2,
              const float* __restrict__ ba2v,
              float* __restrict__ bagAcc)
{
  extern __shared__ char lds[];
  char* Bt0 = lds;                      // [256][128B] bf16, swizzled k
  char* Bt1 = lds + 32768;
  char* HsB = lds;                      // epilogue overlay
  float* sc4  = (float*)(lds + 65536);
  float* evec = (float*)(lds + 65536 + 2048);
  float* Pp   = (float*)(lds + 65536 + 2048 + 512);

  const int tid  = threadIdx.x;
  const int wid  = tid >> 6;
  const int lane = tid & 63;
  const int l15  = lane & 15;
  const int l4   = lane >> 4;
  const int bRow = blockIdx.x * ROWSB;
  const int wRow = wid * 32;            // this wave's private 32 rows

  // ---- A register stream: rows wRow+l15 and wRow+16+l15, k-chunk l4*8 ----
  const float* aG0 = feat + (size_t)(bRow + wRow + l15) * IN_DIM + l4*8;
  const float* aG1 = aG0 + (size_t)16 * IN_DIM;

  // ---- B stage source (linear LDS dest, pre-swizzled global src; rule 21) --
  // dest D(i) = wid*8192 + i*1024 + lane*16: col = D>>7 = wid*64+i*8+(lane>>3),
  // kb_phys = (lane&7)*16. src = w1b + col*2048 + g*128 + (kb ^ ((col&7)<<4)).
  const char* srcB = (const char*)w1b
      + (size_t)(wid*64 + (lane >> 3)) * 2048
      + (((lane & 7) * 16) ^ (((lane >> 3) & 7) << 4));

#define STAGEB(bb, g) do { \
    _Pragma("unroll") \
    for (int i_ = 0; i_ < 8; ++i_) \
      gload_lds16(srcB + (size_t)i_*16384 + (size_t)(g)*128, \
                  (bb) + wid*8192 + i_*1024); \
  } while(0)

#define LOADA(R, t) do { \
    const float* p0_ = aG0 + (t)*32; \
    const float* p1_ = aG1 + (t)*32; \
    R[0] = *(const float4*)p0_;  R[1] = *(const float4*)(p0_ + 4); \
    R[2] = *(const float4*)p1_;  R[3] = *(const float4*)(p1_ + 4); \
  } while(0)

#define AFRAG2(a0, a1, R) do { \
    const float* v_ = (const float*)(R); \
    i32x4 w0_ = { (int)cvtpk(v_[0],  v_[1]),  (int)cvtpk(v_[2],  v_[3]), \
                  (int)cvtpk(v_[4],  v_[5]),  (int)cvtpk(v_[6],  v_[7]) }; \
    i32x4 w1_ = { (int)cvtpk(v_[8],  v_[9]),  (int)cvtpk(v_[10], v_[11]), \
                  (int)cvtpk(v_[12], v_[13]), (int)cvtpk(v_[14], v_[15]) }; \
    a0 = __builtin_bit_cast(short8, w0_); \
    a1 = __builtin_bit_cast(short8, w1_); \
  } while(0)

  f32x4 acc[2][16];
  #pragma unroll
  for (int i = 0; i < 2; ++i)
    #pragma unroll
    for (int j = 0; j < 16; ++j) acc[i][j] = (f32x4){0.f, 0.f, 0.f, 0.f};

  float4 aR0[4], aR1[4];   // A(t even) / A(t odd), 2 rows x 32B each

  // prologue: stage B(0) (oldest), A(0), A(1); retire stage only; barrier
  STAGEB(Bt0, 0);
  LOADA(aR0, 0);
  LOADA(aR1, 1);
  asm volatile("s_waitcnt vmcnt(8)" ::: "memory");
  __builtin_amdgcn_sched_barrier(0);
  __builtin_amdgcn_s_barrier();

  const int swzk = (l15 & 7) << 4;
  const int rb   = l15 * 128;

  for (int g = 0; g < 16; ++g){
    const char* bb = (g & 1) ? Bt1 : Bt0;
    char*       bn = (g & 1) ? Bt0 : Bt1;
    if (g < 15) STAGEB(bn, g + 1);      // in flight across the whole group
    __builtin_amdgcn_sched_barrier(0);

    #pragma unroll
    for (int s = 0; s < 2; ++s){        // t = 2g+s; t&1 == s
      short8 af0, af1;
      if (s == 0){
        AFRAG2(af0, af1, aR0);          // waits A(2g) (issued 2 steps ago)
        if (g < 15) LOADA(aR0, 2*g + 2);
      } else {
        AFRAG2(af0, af1, aR1);          // waits A(2g+1): older than stage(g+1)
        if (g < 15) LOADA(aR1, 2*g + 3);
      }
      __builtin_amdgcn_sched_barrier(0);
      const int off = rb + ((s*64 + l4*16) ^ swzk);
      #pragma unroll
      for (int nf = 0; nf < 16; ++nf){
        short8 bf = *(const short8*)(bb + nf*2048 + off);
        acc[0][nf] = MFMA(af0, bf, acc[0][nf]);
        acc[1][nf] = MFMA(af1, bf, acc[1][nf]);
      }
    }
    // retire stage(g+1) (oldest 8); keep the 8 A prefetch loads in flight
    asm volatile("s_waitcnt vmcnt(8)" ::: "memory");
    __builtin_amdgcn_sched_barrier(0);
    __builtin_amdgcn_s_barrier();
  }
  __syncthreads();   // full drain; Bt region free for Hs overlay

#undef STAGEB
#undef LOADA
#undef AFRAG2

  // -------- epilogue 1: bias + relu, h -> Hs[128][256] bf16 (swizzled) --------
  #pragma unroll
  for (int nf = 0; nf < 16; ++nf){
    float b1v = b1[nf*16 + l15];
    #pragma unroll
    for (int mf = 0; mf < 2; ++mf)
      #pragma unroll
      for (int r = 0; r < 4; ++r){
        int row = wRow + mf*16 + l4*4 + r;
        int col = nf*16 + l15;
        float v = fmaxf(acc[mf][nf][r] + b1v, 0.f);
        int by = (row*512 + col*2) ^ SWZH(row);
        *(unsigned short*)(HsB + by) = f2bf(v);
      }
  }
  __syncthreads();

  // -------- GEMM2: a = h @ Wa1.T (M=128, N=128, K=256); Wa1 from L2 --------
  f32x4 acc2[8][2];
  #pragma unroll
  for (int i = 0; i < 8; ++i)
    #pragma unroll
    for (int j = 0; j < 2; ++j) acc2[i][j] = (f32x4){0.f, 0.f, 0.f, 0.f};

  #pragma unroll
  for (int ks2 = 0; ks2 < 8; ++ks2){
    short8 hf[8], wf[2];
    #pragma unroll
    for (int mf = 0; mf < 8; ++mf){
      int row = mf*16 + l15;
      int by  = (row*512 + (ks2*32 + l4*8)*2) ^ SWZH(row);
      hf[mf] = *(const short8*)(HsB + by);
    }
    #pragma unroll
    for (int nf = 0; nf < 2; ++nf){
      int col = wid*32 + nf*16 + l15;
      wf[nf] = *(const short8*)(const void*)(wa1b + col*256 + ks2*32 + l4*8);
    }
    #pragma unroll
    for (int mf = 0; mf < 8; ++mf)
      #pragma unroll
      for (int nf = 0; nf < 2; ++nf)
        acc2[mf][nf] = MFMA(hf[mf], wf[nf], acc2[mf][nf]);
  }

  // -------- scores: tanh, dot Wa2, reduce across 16-lane col groups --------
  float ba1v[2], wa2v[2];
  #pragma unroll
  for (int nf = 0; nf < 2; ++nf){
    int col = wid*32 + nf*16 + l15;
    ba1v[nf] = ba1[col];
    wa2v[nf] = wa2[col];
  }
  #pragma unroll
  for (int mf = 0; mf < 8; ++mf)
    #pragma unroll
    for (int r = 0; r < 4; ++r){
      float p = tanh_fast(acc2[mf][0][r] + ba1v[0]) * wa2v[0]
              + tanh_fast(acc2[mf][1][r] + ba1v[1]) * wa2v[1];
      p += __shfl_xor(p, 1);
      p += __shfl_xor(p, 2);
      p += __shfl_xor(p, 4);
      p += __shfl_xor(p, 8);
      if (l15 == 0){
        int row = mf*16 + l4*4 + r;
        sc4[row*4 + wid] = p;
      }
    }
  __syncthreads();

  if (tid < 128){
    float s = sc4[tid*4+0] + sc4[tid*4+1] + sc4[tid*4+2] + sc4[tid*4+3] + ba2v[0];
    evec[tid] = __expf(s);   // |s| <= ~2.2 (tanh-bounded) — no max-subtraction
  }
  __syncthreads();

  // -------- weighted partial reduce: P[f] = sum_r e[r]*h[r][f] --------
  {
    const int f0 = (tid & 127) << 1;
    const int g  = tid >> 7;           // 2 row groups of 64
    float p0 = 0.f, p1 = 0.f;
    const int rbase = g << 6;
    #pragma unroll 8
    for (int i = 0; i < 64; ++i){
      const int r = rbase + i;
      const uint32_t hw = *(const uint32_t*)(HsB + ((r*512 + f0*2) ^ SWZH(r)));
      const float e = evec[r];
      p0 = fmaf(e, bf2f((unsigned short)(hw & 0xffffu)), p0);
      p1 = fmaf(e, bf2f((unsigned short)(hw >> 16)),     p1);
    }
    Pp[(g << 8) + f0]     = p0;
    Pp[(g << 8) + f0 + 1] = p1;
  }
  __syncthreads();

  const int bag = bRow >> 13;   // 8192 rows per bag
  {
    float s = Pp[tid] + Pp[256 + tid];
    atomicAdd(&bagAcc[bag*257 + tid], s);
  }
  if (tid < 64){
    float se = evec[tid] + evec[tid + 64];
    se += __shfl_xor(se, 1);
    se += __shfl_xor(se, 2);
    se += __shfl_xor(se, 4);
    se += __shfl_xor(se, 8);
    se += __shfl_xor(se, 16);
    se += __shfl_xor(se, 32);
    if (tid == 0) atomicAdd(&bagAcc[bag*257 + 256], se);
  }
}

// ---------- head: out[b,d] = (P[b]/E[b]) . Wh[d] + bh[d] ----------
__global__ void head_kernel(const float* __restrict__ bagAcc,
                            const float* __restrict__ wh,
                            const float* __restrict__ bh,
                            float* __restrict__ out){
  int t = threadIdx.x;          // 64 threads: b = t>>1, d = t&1
  int b = t >> 1, d = t & 1;
  const float* P = bagAcc + b*257;
  float invE = 1.f / P[256];
  float acc = 0.f;
  for (int f = 0; f < 256; ++f) acc += P[f] * wh[d*256 + f];
  out[b*2 + d] = acc * invE + bh[d];
}

extern "C" void kernel_launch(void* const* d_in, const int* in_sizes, int n_in,
                              void* d_out, int out_size, void* d_ws, size_t ws_size,
                              hipStream_t stream){
  const float* feat = (const float*)d_in[0];
  const float* W1   = (const float*)d_in[1];
  const float* b1   = (const float*)d_in[2];
  const float* Wa1  = (const float*)d_in[3];
  const float* ba1  = (const float*)d_in[4];
  const float* Wa2  = (const float*)d_in[5];
  const float* ba2  = (const float*)d_in[6];
  const float* Wh   = (const float*)d_in[7];
  const float* bh   = (const float*)d_in[8];
  // d_in[9]: bag_sizes — uniform 8192 (N_PATCHES/N_BAGS), bags contiguous.

  unsigned short* w1b  = (unsigned short*)d_ws;                        // 512 KB
  unsigned short* wa1b = (unsigned short*)((char*)d_ws + 524288);      // 64 KB
  float* bagAcc        = (float*)((char*)d_ws + 589824);               // 32*257 f32

  prep_kernel<<<1185, 256, 0, stream>>>(W1, Wa1, w1b, wa1b, bagAcc);

  mil_main<<<NBLK, 256, 70144, stream>>>(feat, w1b, b1, wa1b, ba1,
                                         Wa2, ba2, bagAcc);

  head_kernel<<<1, 64, 0, stream>>>(bagAcc, Wh, bh, (float*)d_out);
}